// Round 5
// baseline (137.465 us; speedup 1.0000x reference)
//
#include <hip/hip_runtime.h>
#include <math.h>
#include <stdint.h>

#define N 4096
#define Dm 1024
#define BM 128
#define BN 128
#define BK 128          // fp8: 128 K-bytes per tile, one mfma_scale K-step per subtile
#define NCB (N / 64)    // 64 column-partials per row

typedef __attribute__((ext_vector_type(8))) int   i32x8;
typedef __attribute__((ext_vector_type(4))) int   i32x4;
typedef __attribute__((ext_vector_type(4))) float f32x4;

typedef const void __attribute__((address_space(1)))* gas_t;
typedef void __attribute__((address_space(3)))* las_t;

static __device__ __forceinline__ void gload_lds16(const void* g, void* l) {
    // async global->LDS, 16B per lane; LDS dest is wave-uniform base + lane*16
    __builtin_amdgcn_global_load_lds((gas_t)g, (las_t)l, 16, 0, 0);
}

// Kernel 1: convert A,P -> fp8 e4m3 (OCP, HW cvt) + per-row diag dot + L2 partial.
// D and rowl2 stay fp32 (exact); only the S-matrix inputs are quantized.
__global__ __launch_bounds__(256) void prep_kernel(const float* __restrict__ A,
                                                   const float* __restrict__ P,
                                                   unsigned char* __restrict__ Af8,
                                                   unsigned char* __restrict__ Pf8,
                                                   float* __restrict__ D,
                                                   float* __restrict__ rowl2) {
    int row = blockIdx.x;
    int t = threadIdx.x;                       // 256 threads x float4 = 1024 floats/row
    const float4* a4 = (const float4*)(A + (size_t)row * Dm);
    const float4* p4 = (const float4*)(P + (size_t)row * Dm);
    float4 a = a4[t], p = p4[t];
    int pa = 0, pp = 0;
    pa = __builtin_amdgcn_cvt_pk_fp8_f32(a.x, a.y, pa, false);
    pa = __builtin_amdgcn_cvt_pk_fp8_f32(a.z, a.w, pa, true);
    pp = __builtin_amdgcn_cvt_pk_fp8_f32(p.x, p.y, pp, false);
    pp = __builtin_amdgcn_cvt_pk_fp8_f32(p.z, p.w, pp, true);
    ((int*)(Af8 + (size_t)row * Dm))[t] = pa;
    ((int*)(Pf8 + (size_t)row * Dm))[t] = pp;
    float dot = a.x * p.x + a.y * p.y + a.z * p.z + a.w * p.w;
    float l2  = a.x * a.x + a.y * a.y + a.z * a.z + a.w * a.w
              + p.x * p.x + p.y * p.y + p.z * p.z + p.w * p.w;
#pragma unroll
    for (int off = 32; off; off >>= 1) {
        dot += __shfl_xor(dot, off, 64);
        l2  += __shfl_xor(l2,  off, 64);
    }
    __shared__ float sd[4], sl[4];
    int wave = t >> 6;
    if ((t & 63) == 0) { sd[wave] = dot; sl[wave] = l2; }
    __syncthreads();
    if (t == 0) {
        D[row]     = sd[0] + sd[1] + sd[2] + sd[3];
        rowl2[row] = sl[0] + sl[1] + sl[2] + sl[3];
    }
}

// Kernel 2: fp8 MX MFMA GEMM (S = A.P^T), 128x128 tile, BK=128 bytes,
// mfma_scale_f32_16x16x128_f8f6f4 with unit scales (127 = E8M0 1.0).
// XOR-swizzled LDS (16B chunk c at position c^(row&7): conflict-free),
// global_load_lds(16B) staging, fused flash-style epilogue.
__global__ __launch_bounds__(256) void npair_mfma(const unsigned char* __restrict__ Af8,
                                                  const unsigned char* __restrict__ Pf8,
                                                  const float* __restrict__ D,
                                                  float* __restrict__ Mpart,
                                                  float* __restrict__ Spart) {
    __shared__ unsigned char At[BM * BK];    // 16 KB, row stride 128 B = 32 banks
    __shared__ unsigned char Bt[BN * BK];    // 16 KB
    __shared__ float Ds[BM];
    int tid = threadIdx.x;
    int wid = tid >> 6, lane = tid & 63;
    int wr = wid >> 1, wc = wid & 1;         // 2x2 waves, each owns 64x64 output
    int row0 = blockIdx.y * BM, col0 = blockIdx.x * BN;

    // Loader: 1024 slots of 16B per tile; slot L = row*8 + c holds global k-chunk (c^(row&7)).
    // Swizzle applied in the GLOBAL fetch address; LDS dest stays lane-ordered.
    const unsigned char* gA[4]; const unsigned char* gB[4];
    unsigned char* lA[4]; unsigned char* lB[4];
#pragma unroll
    for (int b = 0; b < 4; ++b) {
        int L = b * 256 + tid;
        int row = L >> 3, c = L & 7;
        int kch = c ^ (row & 7);
        gA[b] = Af8 + (size_t)(row0 + row) * Dm + (kch << 4);
        gB[b] = Pf8 + (size_t)(col0 + row) * Dm + (kch << 4);
        lA[b] = At + (size_t)L * 16;
        lB[b] = Bt + (size_t)L * 16;
    }
    if (tid < BM) Ds[tid] = D[row0 + tid];

    f32x4 acc[4][4] = {};

    for (int kt = 0; kt < Dm; kt += BK) {    // 8 iterations
        __syncthreads();                      // prior frag reads done before overwrite
#pragma unroll
        for (int b = 0; b < 4; ++b) {
            gload_lds16(gA[b] + kt, lA[b]);
            gload_lds16(gB[b] + kt, lB[b]);
        }
        __syncthreads();                      // drains vmcnt(0): LDS tiles ready

        // A/B frag: lane holds row (lane&15), K-bytes [(lane>>4)*32, +32) = 16B chunks
        // c0=(lane>>4)*2 and c0+1, each at swizzled position (c ^ (row&7)).
        int c0 = (lane >> 4) << 1;
        i32x8 af[4];
#pragma unroll
        for (int i = 0; i < 4; ++i) {
            int arow = wr * 64 + i * 16 + (lane & 15);
            i32x4 lo = *(const i32x4*)(At + arow * BK + (((c0    ) ^ (arow & 7)) << 4));
            i32x4 hi = *(const i32x4*)(At + arow * BK + (((c0 + 1) ^ (arow & 7)) << 4));
            af[i][0] = lo[0]; af[i][1] = lo[1]; af[i][2] = lo[2]; af[i][3] = lo[3];
            af[i][4] = hi[0]; af[i][5] = hi[1]; af[i][6] = hi[2]; af[i][7] = hi[3];
        }
#pragma unroll
        for (int j = 0; j < 4; ++j) {
            int brow = wc * 64 + j * 16 + (lane & 15);
            i32x4 lo = *(const i32x4*)(Bt + brow * BK + (((c0    ) ^ (brow & 7)) << 4));
            i32x4 hi = *(const i32x4*)(Bt + brow * BK + (((c0 + 1) ^ (brow & 7)) << 4));
            i32x8 bf;
            bf[0] = lo[0]; bf[1] = lo[1]; bf[2] = lo[2]; bf[3] = lo[3];
            bf[4] = hi[0]; bf[5] = hi[1]; bf[6] = hi[2]; bf[7] = hi[3];
#pragma unroll
            for (int i = 0; i < 4; ++i)
                acc[i][j] = __builtin_amdgcn_mfma_scale_f32_16x16x128_f8f6f4(
                    af[i], bf, acc[i][j],
                    0, 0,        // cbsz=0 (A fp8 e4m3), blgp=0 (B fp8 e4m3)
                    0, 127,      // scale_a sel byte0, value 127 = 2^0 = 1.0
                    0, 127);     // scale_b sel byte0, value 127 = 1.0
        }
    }

    // Epilogue. C/D layout (shape-determined, m128): col = lane&15, row = (lane>>4)*4 + reg
    int cb = blockIdx.x * 2 + wc;            // column-partial slot, NCB=64 per row
#pragma unroll
    for (int rt = 0; rt < 4; ++rt) {
        int rloc = wr * 64 + rt * 16 + ((lane >> 4) << 2);
#pragma unroll
        for (int e = 0; e < 4; ++e) {
            int gr = row0 + rloc + e;
            float Dv = Ds[rloc + e];
            float xs[4];
            float m = -INFINITY;
#pragma unroll
            for (int ct = 0; ct < 4; ++ct) {
                int gc = col0 + wc * 64 + ct * 16 + (lane & 15);
                float x = acc[rt][ct][e] - Dv;
                if (gr == gc) x = -INFINITY;  // mask diagonal
                xs[ct] = x;
                m = fmaxf(m, x);
            }
#pragma unroll
            for (int off = 8; off; off >>= 1) m = fmaxf(m, __shfl_xor(m, off, 64));
            float s = 0.0f;
#pragma unroll
            for (int ct = 0; ct < 4; ++ct) s += __expf(xs[ct] - m);  // exp(-inf)=0 on diag
#pragma unroll
            for (int off = 8; off; off >>= 1) s += __shfl_xor(s, off, 64);
            if ((lane & 15) == 0) {
                Mpart[(size_t)gr * NCB + cb] = m;
                Spart[(size_t)gr * NCB + cb] = s;
            }
        }
    }
}

// Kernel 3: combine partials per row: loss[i] = m + log(exp(-m) + sum s_k * exp(m_k - m))
__global__ __launch_bounds__(256) void combine_rows(const float* __restrict__ Mpart,
                                                    const float* __restrict__ Spart,
                                                    float* __restrict__ loss) {
    int t = threadIdx.x;
    int lane = t & 63;
    int row = blockIdx.x * 4 + (t >> 6);
    float mp = Mpart[(size_t)row * NCB + lane];
    float sp = Spart[(size_t)row * NCB + lane];
    float m = mp;
#pragma unroll
    for (int off = 32; off; off >>= 1) m = fmaxf(m, __shfl_xor(m, off, 64));
    float s = sp * __expf(mp - m);
#pragma unroll
    for (int off = 32; off; off >>= 1) s += __shfl_xor(s, off, 64);
    if (lane == 0) loss[row] = m + logf(__expf(-m) + s);   // log1p(sum exp(x)), overflow-safe
}

// Kernel 4: final scalar: mean(loss) + 0.02 * sum(rowl2)/N
__global__ __launch_bounds__(256) void final_reduce(const float* __restrict__ loss,
                                                    const float* __restrict__ rowl2,
                                                    float* __restrict__ out) {
    int t = threadIdx.x;
    float accL = 0.0f, acc2 = 0.0f;
    for (int i = t; i < N; i += 256) {
        accL += loss[i];
        acc2 += rowl2[i];
    }
#pragma unroll
    for (int off = 32; off; off >>= 1) {
        accL += __shfl_xor(accL, off, 64);
        acc2 += __shfl_xor(acc2, off, 64);
    }
    __shared__ float sa[4], sb[4];
    int wave = t >> 6;
    if ((t & 63) == 0) { sa[wave] = accL; sb[wave] = acc2; }
    __syncthreads();
    if (t == 0) {
        float L  = sa[0] + sa[1] + sa[2] + sa[3];
        float l2 = sb[0] + sb[1] + sb[2] + sb[3];
        out[0] = L / (float)N + 0.02f * (l2 / (float)N);
    }
}

extern "C" void kernel_launch(void* const* d_in, const int* in_sizes, int n_in,
                              void* d_out, int out_size, void* d_ws, size_t ws_size,
                              hipStream_t stream) {
    const float* A = (const float*)d_in[0];
    const float* P = (const float*)d_in[1];
    float* out = (float*)d_out;

    unsigned char* Af8 = (unsigned char*)d_ws;              // N*Dm fp8 = 4 MiB
    unsigned char* Pf8 = Af8 + (size_t)N * Dm;              // 4 MiB
    float* D     = (float*)(Pf8 + (size_t)N * Dm);          // N
    float* rowl2 = D + N;                                   // N
    float* loss  = rowl2 + N;                               // N
    float* Mpart = loss + N;                                // N*NCB = 1 MiB
    float* Spart = Mpart + (size_t)N * NCB;                 // 1 MiB

    prep_kernel<<<N, 256, 0, stream>>>(A, P, Af8, Pf8, D, rowl2);
    dim3 grid(N / BN, N / BM);
    npair_mfma<<<grid, 256, 0, stream>>>(Af8, Pf8, D, Mpart, Spart);
    combine_rows<<<N / 4, 256, 0, stream>>>(Mpart, Spart, loss);
    final_reduce<<<1, 256, 0, stream>>>(loss, rowl2, out);
}